// Round 2
// 358.099 us; speedup vs baseline: 1.1779x; 1.1779x over previous
//
#include <hip/hip_runtime.h>
#include <math.h>

// Sizes: K=4, B=1024, C=128, T=64, D=64, H=4, HD=16, N=B*D=65536
#define EPSV 1e-5f

typedef __attribute__((ext_vector_type(8))) short short8;   // 8 x bf16 (4 VGPRs)
typedef __attribute__((ext_vector_type(4))) float float4v;  // MFMA 16x16 acc

__device__ __forceinline__ unsigned short f2bf(float f) {   // fp32 -> bf16 RNE
  unsigned int x = __float_as_uint(f);
  return (unsigned short)((x + 0x7fffu + ((x >> 16) & 1u)) >> 16);
}
__device__ __forceinline__ float bf2f(unsigned short u) {
  return __uint_as_float(((unsigned int)u) << 16);
}
__device__ __forceinline__ float wave_sum64(float v) {
  v += __shfl_xor(v, 1);
  v += __shfl_xor(v, 2);
  v += __shfl_xor(v, 4);
  v += __shfl_xor(v, 8);
  v += __shfl_xor(v, 16);
  v += __shfl_xor(v, 32);
  return v;
}
__device__ __forceinline__ float group16_sum(float v) {     // sum over lane&15 group
  v += __shfl_xor(v, 1);
  v += __shfl_xor(v, 2);
  v += __shfl_xor(v, 4);
  v += __shfl_xor(v, 8);
  return v;
}
// Wave-level LDS fence: orders this wave's LDS writes before subsequent LDS
// reads (lanes are lockstep, so wave-private LDS needs no __syncthreads).
// The "memory" clobber stops the compiler reordering its own LDS ops across it.
__device__ __forceinline__ void lds_fence() {
  asm volatile("s_waitcnt lgkmcnt(0)" ::: "memory");
}

// ---------------------------------------------------------------------------
// Kernel 0: one-time weight prep.
//   proj_w -> split bf16 hi/lo (hi+lo ~= fp32: keeps proj at fp32 precision)
//   wq/wk/wv/wo -> bf16, grouped per module: wb[(i*4+mat)*4096 + n*64 + k]
// grid 384*256 = 98304 = 32768 (proj_w) + 65536 (attn weights), exact.
// ---------------------------------------------------------------------------
__global__ __launch_bounds__(256) void prep_kernel(
    const float* __restrict__ pw, const float* __restrict__ wq,
    const float* __restrict__ wk, const float* __restrict__ wv,
    const float* __restrict__ wo, unsigned short* __restrict__ wph,
    unsigned short* __restrict__ wpl, unsigned short* __restrict__ wb) {
  int idx = blockIdx.x * 256 + threadIdx.x;
  if (idx < 32768) {
    float f = pw[idx];
    unsigned short h = f2bf(f);
    wph[idx] = h;
    wpl[idx] = f2bf(f - bf2f(h));
  } else {
    int e = idx - 32768;
    int mat = e >> 14, i = (e >> 12) & 3, r = e & 4095;
    const float* src = (mat == 0) ? wq : (mat == 1) ? wk : (mat == 2) ? wv : wo;
    wb[((i * 4 + mat) << 12) + r] = f2bf(src[(i << 12) + r]);
  }
}

// ---------------------------------------------------------------------------
// Kernel 1: proj as split-bf16 MFMA. Per block (k,b): D=64 x T=64, K=C=128.
//   A[m=d][k=c] = proj_w[d][c]   (global bf16 hi/lo, contiguous fragments)
//   B[k=c][n=t] = feats[c][t]    (LDS transposed [t][c], stride 136 shorts)
// 3-term product (wh*fh + wh*fl + wl*fh) ~ fp32. Output written as bf16 ctx
// (identical f2bf rounding the old attn kernel applied on staging).
// ---------------------------------------------------------------------------
__global__ __launch_bounds__(256, 4) void proj_kernel(
    const float* __restrict__ feats, const unsigned short* __restrict__ wph,
    const unsigned short* __restrict__ wpl, const float* __restrict__ pb,
    unsigned short* __restrict__ ctxbf) {
  int kb = blockIdx.x;          // kb = k*1024 + b
  int k = kb >> 10;
  int b = kb & 1023;

  __shared__ __align__(16) unsigned short FH[64 * 136];   // [t][c] hi
  __shared__ __align__(16) unsigned short FL[64 * 136];   // [t][c] lo

  int tid = threadIdx.x;
  const float* fsrc = feats + (size_t)kb * 8192;
  for (int u = tid; u < 2048; u += 256) {                 // float4 units
    float4 f = *(const float4*)&fsrc[u * 4];
    int c = u >> 4;                 // (u*4)>>6
    int t0 = (u & 15) * 4;          // (u*4)&63
#pragma unroll
    for (int q = 0; q < 4; ++q) {
      float fv = (q == 0) ? f.x : (q == 1) ? f.y : (q == 2) ? f.z : f.w;
      unsigned short h = f2bf(fv);
      FH[(t0 + q) * 136 + c] = h;
      FL[(t0 + q) * 136 + c] = f2bf(fv - bf2f(h));
    }
  }
  __syncthreads();

  int w = tid >> 6, l = tid & 63;
  int l15 = l & 15, lq = l >> 4;

  const float4v zf = {0.0f, 0.0f, 0.0f, 0.0f};
  float4v acc[4] = {zf, zf, zf, zf};                      // wave owns d-tile mt=w

  const unsigned short* whp = wph + k * 8192 + (w * 16 + l15) * 128 + lq * 8;
  const unsigned short* wlp = wpl + k * 8192 + (w * 16 + l15) * 128 + lq * 8;

#pragma unroll
  for (int kc = 0; kc < 4; ++kc) {
    short8 ah = *(const short8*)&whp[kc * 32];
    short8 al = *(const short8*)&wlp[kc * 32];
#pragma unroll
    for (int nt = 0; nt < 4; ++nt) {
      short8 bh = *(const short8*)&FH[(nt * 16 + l15) * 136 + kc * 32 + lq * 8];
      short8 bl = *(const short8*)&FL[(nt * 16 + l15) * 136 + kc * 32 + lq * 8];
      acc[nt] = __builtin_amdgcn_mfma_f32_16x16x32_bf16(ah, bh, acc[nt], 0, 0, 0);
      acc[nt] = __builtin_amdgcn_mfma_f32_16x16x32_bf16(ah, bl, acc[nt], 0, 0, 0);
      acc[nt] = __builtin_amdgcn_mfma_f32_16x16x32_bf16(al, bh, acc[nt], 0, 0, 0);
    }
  }

  float pbv[4];
#pragma unroll
  for (int r = 0; r < 4; ++r) pbv[r] = pb[k * 64 + w * 16 + lq * 4 + r];

  // d = w*16 + lq*4 + r, t = nt*16 + l15
  // ctx row n = b*64 + k*16 + (d>>2) = b*64 + k*16 + w*4 + lq; col = (d&3)*64 + t
  size_t base = ((size_t)b * 64 + k * 16 + w * 4 + lq) * 256;
#pragma unroll
  for (int nt = 0; nt < 4; ++nt)
#pragma unroll
    for (int r = 0; r < 4; ++r)
      ctxbf[base + r * 64 + nt * 16 + l15] = f2bf(acc[nt][r] + pbv[r]);
}

// ---------------------------------------------------------------------------
// Kernel 2: MFMA attention — barrier-free.
// All LDS is wave-private: wave w stages only its 16 ctx rows; OSP[w] is its
// own o-slab. Weight B-fragments come straight from the prepped global wb
// (L1-resident: 32KB/module reused by every wave). K/V fragments are hoisted
// into registers across the j-loop. Zero __syncthreads.
// ---------------------------------------------------------------------------
__global__ __launch_bounds__(256, 2) void attn_fused(
    const unsigned short* __restrict__ ctxbf,
    const unsigned short* __restrict__ wb,
    const float* __restrict__ bq, const float* __restrict__ bk,
    const float* __restrict__ bv, const float* __restrict__ bo,
    const float* __restrict__ ng, const float* __restrict__ nb,
    const float* __restrict__ tfw, float* __restrict__ out) {
  __shared__ __align__(16) unsigned short CTP[64 * 264];   // ctx rows, pad 256->264
  __shared__ __align__(16) unsigned short OSP[4][16 * 72]; // per-wave o slab

  int tid = threadIdx.x;
  int w = tid >> 6, l = tid & 63;
  int l15 = l & 15, lq = l >> 4;

  // per-wave stage of this wave's 16 ctx rows (bf16 -> bf16, vector copies)
  {
    const unsigned short* csrc = ctxbf + ((size_t)blockIdx.x * 64 + w * 16) * 256;
#pragma unroll
    for (int u = 0; u < 8; ++u) {
      int e = u * 64 + l;                 // 512 short8 units: 16 rows x 32
      int row = e >> 5, c8 = (e & 31) * 8;
      *(short8*)&CTP[(w * 16 + row) * 264 + c8] =
          *(const short8*)&csrc[row * 256 + c8];
    }
  }
  lds_fence();

  // softmax(tfw)
  float tf0 = tfw[0], tf1 = tfw[1], tf2 = tfw[2], tf3 = tfw[3];
  float tm = fmaxf(fmaxf(tf0, tf1), fmaxf(tf2, tf3));
  float te0 = __expf(tf0 - tm), te1 = __expf(tf1 - tm);
  float te2 = __expf(tf2 - tm), te3 = __expf(tf3 - tm);
  float tden = te0 + te1 + te2 + te3;

  const unsigned short* arow = &CTP[(w * 16 + l15) * 264];
  const float4v zf = {0.0f, 0.0f, 0.0f, 0.0f};

#pragma unroll 1
  for (int i = 0; i < 4; ++i) {
#define WFRAG(m, nt, s)                                                        \
  (*(const short8*)&wb[((i * 4 + (m)) << 12) + ((nt)*16 + l15) * 64 +          \
                       (s)*32 + lq * 8])

    float wi = ((i == 0) ? te0 : (i == 1) ? te1 : (i == 2) ? te2 : te3) / tden;

    float bqv[4], bkv[4], bvv[4];
#pragma unroll
    for (int nt = 0; nt < 4; ++nt) {
      int d = i * 64 + nt * 16 + l15;
      bqv[nt] = bq[d]; bkv[nt] = bk[d]; bvv[nt] = bv[d];
    }

    // ---- q = ctx[:,i] @ wq^T + bq ----
    float4v qacc[4] = {zf, zf, zf, zf};
#pragma unroll
    for (int s = 0; s < 2; ++s) {
      short8 af = *(const short8*)&arow[i * 64 + s * 32 + lq * 8];
#pragma unroll
      for (int nt = 0; nt < 4; ++nt)
        qacc[nt] = __builtin_amdgcn_mfma_f32_16x16x32_bf16(af, WFRAG(0, nt, s),
                                                           qacc[nt], 0, 0, 0);
    }
#pragma unroll
    for (int nt = 0; nt < 4; ++nt)
#pragma unroll
      for (int r = 0; r < 4; ++r) qacc[nt][r] += bqv[nt];

    // hoist K/V B-fragments into registers (reused 4x each in the j-loop)
    short8 kf[2][4], vf[2][4];
#pragma unroll
    for (int s = 0; s < 2; ++s)
#pragma unroll
      for (int nt = 0; nt < 4; ++nt) {
        kf[s][nt] = WFRAG(1, nt, s);
        vf[s][nt] = WFRAG(2, nt, s);
      }

    // ---- per key j: k/v GEMMs, scores, un-normalized softmax-weighted V ----
    float4v oacc[4] = {zf, zf, zf, zf};
    float lsum[4][4] = {{0,0,0,0},{0,0,0,0},{0,0,0,0},{0,0,0,0}};

#pragma unroll 1
    for (int j = 0; j < 4; ++j) {
      float4v kacc[4] = {zf, zf, zf, zf};
      float4v vacc[4] = {zf, zf, zf, zf};
#pragma unroll
      for (int s = 0; s < 2; ++s) {
        short8 af = *(const short8*)&arow[j * 64 + s * 32 + lq * 8];
#pragma unroll
        for (int nt = 0; nt < 4; ++nt) {
          kacc[nt] = __builtin_amdgcn_mfma_f32_16x16x32_bf16(af, kf[s][nt],
                                                             kacc[nt], 0, 0, 0);
          vacc[nt] = __builtin_amdgcn_mfma_f32_16x16x32_bf16(af, vf[s][nt],
                                                             vacc[nt], 0, 0, 0);
        }
      }
#pragma unroll
      for (int nt = 0; nt < 4; ++nt)
#pragma unroll
        for (int r = 0; r < 4; ++r) {
          float p = qacc[nt][r] * (kacc[nt][r] + bkv[nt]);
          p = group16_sum(p) * 0.25f;          // 1/sqrt(HD); |p| small -> no max-sub
          float e = __expf(p);
          lsum[nt][r] += e;
          oacc[nt][r] += e * (vacc[nt][r] + bvv[nt]);
        }
    }

    // ---- o (C/D layout) -> plain [m][d] slab (wave-private, fence only) ----
    lds_fence();   // order vs previous iteration's OSP reads
#pragma unroll
    for (int nt = 0; nt < 4; ++nt)
#pragma unroll
      for (int r = 0; r < 4; ++r)
        OSP[w][(lq * 4 + r) * 72 + nt * 16 + l15] = f2bf(oacc[nt][r] / lsum[nt][r]);
    lds_fence();

    // ---- o2 = o @ wo^T ----
    float4v o2[4] = {zf, zf, zf, zf};
#pragma unroll
    for (int s = 0; s < 2; ++s) {
      short8 af = *(const short8*)&OSP[w][l15 * 72 + s * 32 + lq * 8];
#pragma unroll
      for (int nt = 0; nt < 4; ++nt)
        o2[nt] = __builtin_amdgcn_mfma_f32_16x16x32_bf16(af, WFRAG(3, nt, s),
                                                         o2[nt], 0, 0, 0);
    }

    float bov[4], ngv[4], nbv[4];
#pragma unroll
    for (int nt = 0; nt < 4; ++nt) {
      int d = i * 64 + nt * 16 + l15;
      bov[nt] = bo[d]; ngv[nt] = ng[d]; nbv[nt] = nb[d];
    }

    // ---- + bo + residual (plain CTP read) ----
    float rr[4][4];
#pragma unroll
    for (int nt = 0; nt < 4; ++nt)
#pragma unroll
      for (int r = 0; r < 4; ++r) {
        float qin = bf2f(CTP[(w * 16 + lq * 4 + r) * 264 + i * 64 + nt * 16 + l15]);
        rr[nt][r] = o2[nt][r] + bov[nt] + qin;
      }

    // ---- per-module LN over 64 dims of row m = lq*4+r; scale by wi; store ----
#pragma unroll
    for (int r = 0; r < 4; ++r) {
      float sm = group16_sum(rr[0][r] + rr[1][r] + rr[2][r] + rr[3][r]) * (1.0f / 64.0f);
      float vs = 0.0f;
#pragma unroll
      for (int nt = 0; nt < 4; ++nt) { float dx = rr[nt][r] - sm; vs += dx * dx; }
      vs = group16_sum(vs) * (1.0f / 64.0f);
      float inv = rsqrtf(vs + EPSV);
      size_t row = (size_t)blockIdx.x * 64 + w * 16 + lq * 4 + r;
#pragma unroll
      for (int nt = 0; nt < 4; ++nt) {
        float val = wi * ((rr[nt][r] - sm) * inv * ngv[nt] + nbv[nt]);
        out[row * 256 + i * 64 + nt * 16 + l15] = val;
      }
    }
#undef WFRAG
  }
}

// ---------------------------------------------------------------------------
// Kernel 3 (proven, unchanged): final LN over K*D=256, in place.
// ---------------------------------------------------------------------------
__global__ __launch_bounds__(256, 4) void final_ln_kernel(
    float* __restrict__ out, const float* __restrict__ fg,
    const float* __restrict__ fb) {
  int lane = threadIdx.x & 63;
  int wave = threadIdx.x >> 6;
  size_t n = (size_t)blockIdx.x * 4 + wave;

  float4 v = *(const float4*)&out[n * 256 + lane * 4];
  float mean = wave_sum64(v.x + v.y + v.z + v.w) * (1.0f / 256.0f);
  float dx = v.x - mean, dy = v.y - mean, dz = v.z - mean, dw = v.w - mean;
  float var = wave_sum64(dx * dx + dy * dy + dz * dz + dw * dw) * (1.0f / 256.0f);
  float inv = rsqrtf(var + EPSV);

  float4 g = *(const float4*)&fg[lane * 4];
  float4 bb = *(const float4*)&fb[lane * 4];
  float4 o;
  o.x = dx * inv * g.x + bb.x;
  o.y = dy * inv * g.y + bb.y;
  o.z = dz * inv * g.z + bb.z;
  o.w = dw * inv * g.w + bb.w;
  *(float4*)&out[n * 256 + lane * 4] = o;
}

// ---------------------------------------------------------------------------
extern "C" void kernel_launch(void* const* d_in, const int* in_sizes, int n_in,
                              void* d_out, int out_size, void* d_ws, size_t ws_size,
                              hipStream_t stream) {
  const float* feats  = (const float*)d_in[0];
  const float* proj_w = (const float*)d_in[1];
  const float* proj_b = (const float*)d_in[2];
  const float* wq  = (const float*)d_in[3];
  const float* wk  = (const float*)d_in[4];
  const float* wv  = (const float*)d_in[5];
  const float* bq  = (const float*)d_in[6];
  const float* bk  = (const float*)d_in[7];
  const float* bv  = (const float*)d_in[8];
  const float* wo  = (const float*)d_in[9];
  const float* bo  = (const float*)d_in[10];
  const float* ng  = (const float*)d_in[11];
  const float* nb  = (const float*)d_in[12];
  const float* tfw = (const float*)d_in[13];
  const float* fg  = (const float*)d_in[14];
  const float* fb  = (const float*)d_in[15];
  float* out = (float*)d_out;

  // workspace: ctx_bf 32MB | wph 64KB | wpl 64KB | wb 128KB
  unsigned short* ctxbf = (unsigned short*)d_ws;
  unsigned short* wph = (unsigned short*)((char*)d_ws + ((size_t)32 << 20));
  unsigned short* wpl = wph + 32768;
  unsigned short* wb  = wpl + 32768;

  prep_kernel<<<384, 256, 0, stream>>>(proj_w, wq, wk, wv, wo, wph, wpl, wb);
  proj_kernel<<<4096, 256, 0, stream>>>(feats, wph, wpl, proj_b, ctxbf);
  attn_fused<<<1024, 256, 0, stream>>>(ctxbf, wb, bq, bk, bv, bo,
                                       ng, nb, tfw, out);
  final_ln_kernel<<<16384, 256, 0, stream>>>(out, fg, fb);
}